// Round 1
// 622.510 us; speedup vs baseline: 1.0992x; 1.0992x over previous
//
#include <hip/hip_runtime.h>
#include <cstdint>

// Problem constants (from reference)
constexpr int G = 4, N = 50000, E = 800000;
constexpr int FIN = 64, HID = 128, FOUT = 64;
constexpr int NB = (N + 1023) / 1024;  // scan blocks per graph = 49

// Counting-sort CSR build parameters
constexpr int BE = 32;       // edge chunks per graph
constexpr int CE = E / BE;   // 25000 edges per chunk (exact)
constexpr int NHH = N / 2;   // 25000 nodes per half (u16-packed LDS = 50KB)

typedef unsigned short ushort;

__device__ __forceinline__ ushort f2bf(float f) {  // RNE
  uint32_t u = __builtin_bit_cast(uint32_t, f);
  u += 0x7FFF + ((u >> 16) & 1);
  return (ushort)(u >> 16);
}
__device__ __forceinline__ float bf2f(ushort h) {
  uint32_t u = (uint32_t)h << 16;
  return __builtin_bit_cast(float, u);
}

// XCD-confined swizzle: block b -> XCD (b&7), 2 XCDs per graph.
// Requires G*N/4 = 50000 blocks; per graph 12500 chunks of 4 nodes.
__device__ __forceinline__ void xcd_map(int b, int& g, int& chunk) {
  int xcd = b & 7;
  int sub = b >> 3;  // 0..6249
  g = xcd >> 1;
  chunk = (xcd & 1) * 6250 + sub;  // 0..12499
}

// ---------------- CSR build: LDS counting sort (ZERO device atomics) ----------------
// R6: k_deg's 3.2M device-scope atomicAdd-with-return were memory-side RMWs
// (WRITE_SIZE 112MB, 22G atomics/s, 143us). Replaced by block-private LDS
// histograms: per (g, node-half, edge-chunk) block, u16-packed counts in
// u32[12500] = 50KB LDS. Counts <= CE=25000 so u16 never overflows and the
// packed add never carries across the halfword boundary.

__global__ __launch_bounds__(256) void k_hist(const int* __restrict__ ei,
                                              ushort* __restrict__ H) {
  __shared__ unsigned h[NHH / 2];  // 12500 words, 2 nodes/word (lo=even,hi=odd)
  int be = blockIdx.x, half = blockIdx.y, g = blockIdx.z;
  for (int i = threadIdx.x; i < NHH / 2; i += 256) h[i] = 0;
  __syncthreads();
  int h0 = half * NHH;
  const int4* dst4 = (const int4*)(ei + (size_t)g * 2 * E + E + (size_t)be * CE);
  for (int i = threadIdx.x; i < CE / 4; i += 256) {
    int4 d = dst4[i];
    int dv[4] = {d.x, d.y, d.z, d.w};
#pragma unroll
    for (int k = 0; k < 4; ++k) {
      int n = dv[k] - h0;
      if ((unsigned)n < (unsigned)NHH)
        atomicAdd(&h[n >> 1], 1u << ((n & 1) * 16));  // ds_add, no return
    }
  }
  __syncthreads();
  // H[g][be][n] as u16; write packed pairs (little-endian matches lo/hi)
  unsigned* Hw = (unsigned*)(H + ((size_t)g * BE + be) * N + h0);
  for (int i = threadIdx.x; i < NHH / 2; i += 256) Hw[i] = h[i];
}

// cnt[g][n] = sum_be H[g][be][n]  (replaces atomic counting + k_zero)
__global__ void k_reduce(const ushort* __restrict__ H, int* __restrict__ cnt) {
  int i = blockIdx.x * blockDim.x + threadIdx.x;  // over G*N/2
  if (i >= G * N / 2) return;
  int g = i / (N / 2), nw = i - g * (N / 2);
  const unsigned* Hw = (const unsigned*)(H + (size_t)g * BE * N) + nw;
  unsigned s0 = 0, s1 = 0;
#pragma unroll 8
  for (int be = 0; be < BE; ++be) {
    unsigned v = Hw[(size_t)be * (N / 2)];
    s0 += v & 0xffffu;
    s1 += v >> 16;
  }
  int2 c = {(int)s0, (int)s1};
  *(int2*)(cnt + (size_t)g * N + 2 * nw) = c;
}

// OFF[g][be][n] = rowptr[g][n] + sum_{be'<be} H[g][be'][n]
__global__ void k_off(const ushort* __restrict__ H, const int* __restrict__ rowptr,
                      int* __restrict__ OFF) {
  int i = blockIdx.x * blockDim.x + threadIdx.x;  // over G*N/2
  if (i >= G * N / 2) return;
  int g = i / (N / 2), nw = i - g * (N / 2);
  const unsigned* Hw = (const unsigned*)(H + (size_t)g * BE * N) + nw;
  // rowptr stride N+1 is odd -> scalar loads (int2 would misalign for odd g)
  int a0 = rowptr[(size_t)g * (N + 1) + 2 * nw];
  int a1 = rowptr[(size_t)g * (N + 1) + 2 * nw + 1];
  int* Ob = OFF + (size_t)g * BE * N + 2 * nw;
#pragma unroll 4
  for (int be = 0; be < BE; ++be) {
    unsigned v = Hw[(size_t)be * (N / 2)];
    int2 o = {a0, a1};
    *(int2*)(Ob + (size_t)be * N) = o;
    a0 += (int)(v & 0xffffu);
    a1 += (int)(v >> 16);
  }
}

// atomic-free-at-device fill: rank from returning LDS atomic, base from OFF
// (per-block OFF slice is 200KB -> L2-resident gather)
__global__ __launch_bounds__(256) void k_fill2(const int* __restrict__ ei,
                                               const int* __restrict__ OFF,
                                               int* __restrict__ col) {
  __shared__ unsigned rk[NHH / 2];  // packed u16 ranks, 50KB
  int be = blockIdx.x, half = blockIdx.y, g = blockIdx.z;
  int h0 = half * NHH;
  for (int i = threadIdx.x; i < NHH / 2; i += 256) rk[i] = 0;
  __syncthreads();
  const int* srcA = ei + (size_t)g * 2 * E + (size_t)be * CE;
  const int4* src4 = (const int4*)srcA;
  const int4* dst4 = (const int4*)(srcA + E);
  const int* Ob = OFF + ((size_t)g * BE + be) * N;
  int* cg = col + (size_t)g * E;
  for (int i = threadIdx.x; i < CE / 4; i += 256) {
    int4 d = dst4[i];
    int4 s = src4[i];
    int dv[4] = {d.x, d.y, d.z, d.w};
    int sv[4] = {s.x, s.y, s.z, s.w};
#pragma unroll
    for (int k = 0; k < 4; ++k) {
      int n = dv[k] - h0;
      if ((unsigned)n < (unsigned)NHH) {
        unsigned old = atomicAdd(&rk[n >> 1], 1u << ((n & 1) * 16));
        int rank = (int)((old >> ((n & 1) * 16)) & 0xffffu);
        cg[Ob[dv[k]] + rank] = sv[k];
      }
    }
  }
}

// ---- 3-kernel exclusive scan of cnt -> rowptr (per graph) ----
__global__ void k_scan_partial(const int* __restrict__ cnt, int* __restrict__ part) {
  int g = blockIdx.y, b = blockIdx.x, tid = threadIdx.x;
  int base = b * 1024 + tid * 4;
  int s = 0;
#pragma unroll
  for (int k = 0; k < 4; ++k) {
    int i = base + k;
    if (i < N) s += cnt[g * N + i];
  }
  __shared__ int sm[256];
  sm[tid] = s;
  __syncthreads();
  for (int off = 128; off > 0; off >>= 1) {
    if (tid < off) sm[tid] += sm[tid + off];
    __syncthreads();
  }
  if (tid == 0) part[g * NB + b] = sm[0];
}

__global__ void k_scan_mid(int* __restrict__ part, int* __restrict__ rowptr) {
  int g = blockIdx.x;
  if (threadIdx.x != 0) return;
  int run = 0;
  for (int b = 0; b < NB; ++b) {
    int t = part[g * NB + b];
    part[g * NB + b] = run;
    run += t;
  }
  rowptr[g * (N + 1) + N] = run;  // == E
}

// final scan + fused dinv computation
__global__ void k_scan_final(const int* __restrict__ cnt, const int* __restrict__ part,
                             int* __restrict__ rowptr, float* __restrict__ dinv) {
  int g = blockIdx.y, b = blockIdx.x, tid = threadIdx.x;
  int base = b * 1024 + tid * 4;
  int c[4];
  int s = 0;
#pragma unroll
  for (int k = 0; k < 4; ++k) {
    int i = base + k;
    c[k] = (i < N) ? cnt[g * N + i] : 0;
    s += c[k];
  }
  __shared__ int sm[256];
  sm[tid] = s;
  __syncthreads();
  for (int off = 1; off < 256; off <<= 1) {
    int v = (tid >= off) ? sm[tid - off] : 0;
    __syncthreads();
    sm[tid] += v;
    __syncthreads();
  }
  int excl = sm[tid] - s + part[g * NB + b];
#pragma unroll
  for (int k = 0; k < 4; ++k) {
    int i = base + k;
    if (i < N) {
      rowptr[g * (N + 1) + i] = excl;
      dinv[g * N + i] = rsqrtf((float)(c[k] + 1));  // +1 self loop
    }
    excl += c[k];
  }
}

// ---------------- LDS-staged GEMM: columns across waves, lane = row ----------------
// Block = 256 threads = 4 waves, covers 64 rows. X tile staged ONCE in LDS
// (padded row stride K+1 -> (lane+k)%32 bank map, 2 lanes/bank = free).
// Wave w computes columns [w*F/4, (w+1)*F/4) for all 64 rows.
// c0 forced into an SGPR via readfirstlane so the W address chain is provably
// scalar -> batched s_load through the constant cache on the scalar pipe
// (R5 bug: threadIdx-derived c0 failed divergence analysis -> per-lane
// global_load_dword, VMEM-issue bound, 230 us).
template <int K, int F, bool PRESCALE, bool BIASELU, bool OUTBF>
__global__ __launch_bounds__(256) void k_gemm_lds(const float* __restrict__ X,
                                                  const float* __restrict__ W,
                                                  const float* __restrict__ dinv,
                                                  const float* __restrict__ bias,
                                                  void* __restrict__ Hout) {
  constexpr int CH = F / 4;  // columns per wave (32 or 16)
  constexpr int PK = K + 1;  // padded LDS row stride
  __shared__ float xs[64 * PK];
  int g = blockIdx.y;
  int R0 = blockIdx.x * 64;
  // stage 64 rows (coalesced global read, conflict-free LDS write)
  for (int idx = threadIdx.x; idx < 64 * K; idx += 256) {
    int r = idx / K, k = idx - r * K;
    int row = R0 + r;
    xs[r * PK + k] = (row < N) ? X[((size_t)g * N + row) * K + k] : 0.f;
  }
  __syncthreads();
  int wv = threadIdx.x >> 6;
  int lane = threadIdx.x & 63;
  int c0 = __builtin_amdgcn_readfirstlane(wv * CH);  // SGPR column base
  const float* Wg = W + (size_t)g * K * F;
  const float* xrow = &xs[lane * PK];
  float acc[CH];
#pragma unroll
  for (int c = 0; c < CH; ++c) acc[c] = 0.f;
#pragma unroll 4
  for (int k = 0; k < K; ++k) {
    float xv = xrow[k];
#pragma unroll
    for (int c = 0; c < CH; ++c)
      acc[c] = fmaf(xv, Wg[(size_t)k * F + c0 + c], acc[c]);
  }
  int row = R0 + lane;
  if (row >= N) return;
  if constexpr (PRESCALE) {
    float sc = dinv[g * N + row];
#pragma unroll
    for (int c = 0; c < CH; ++c) acc[c] *= sc;
  }
  if constexpr (BIASELU) {
#pragma unroll
    for (int c = 0; c < CH; ++c) {
      float v = acc[c] + bias[g * F + c0 + c];
      acc[c] = v > 0.f ? v : expm1f(v);
    }
  }
  if constexpr (OUTBF) {
    ushort* opb = (ushort*)Hout + ((size_t)g * N + row) * F + c0;
#pragma unroll
    for (int c4 = 0; c4 < CH; c4 += 4) {
      ushort4 o = {f2bf(acc[c4]), f2bf(acc[c4 + 1]), f2bf(acc[c4 + 2]),
                   f2bf(acc[c4 + 3])};
      *(ushort4*)(opb + c4) = o;
    }
  } else {
    float* op = (float*)Hout + ((size_t)g * N + row) * F + c0;
#pragma unroll
    for (int c4 = 0; c4 < CH; c4 += 4) {
      float4 o = {acc[c4], acc[c4 + 1], acc[c4 + 2], acc[c4 + 3]};
      *(float4*)(op + c4) = o;
    }
  }
}

// ---------------- aggregate-first (layer 1): Z = D^-1/2 (A+I) D^-1/2 X ----------------
// one wave per dst node; F = 64 (1 float/lane); dinv[s] folded in via shfl broadcast
template <int F>
__global__ __launch_bounds__(256) void k_agg_in(const float* __restrict__ X,
                                                const int* __restrict__ rowptr,
                                                const int* __restrict__ col,
                                                const float* __restrict__ dinv,
                                                float* __restrict__ Z) {
  int g, chunk;
  xcd_map(blockIdx.x, g, chunk);
  int d = chunk * 4 + (threadIdx.x >> 6);
  int lane = threadIdx.x & 63;
  const float* hb = X + (size_t)g * N * F;
  const float* dv = dinv + g * N;
  const int* cl = col + (size_t)g * E;
  int rs = rowptr[g * (N + 1) + d];
  int re = rowptr[g * (N + 1) + d + 1];
  float dd = dv[d];
  float acc = dd * hb[(size_t)d * F + lane];  // self loop
  for (int j0 = rs; j0 < re; j0 += 64) {
    int idx = j0 + lane;
    int myc = (idx < re) ? cl[idx] : 0;
    float myd = (idx < re) ? dv[myc] : 0.f;
    int nn = min(64, re - j0);
    int jj = 0;
    for (; jj + 8 <= nn; jj += 8) {
      int s[8];
      float sw[8];
#pragma unroll
      for (int k = 0; k < 8; ++k) {
        s[k] = __shfl(myc, jj + k, 64);
        sw[k] = __shfl(myd, jj + k, 64);
      }
      float v[8];
#pragma unroll
      for (int k = 0; k < 8; ++k) v[k] = hb[(size_t)s[k] * F + lane];
#pragma unroll
      for (int k = 0; k < 8; ++k) acc += sw[k] * v[k];
    }
    for (; jj < nn; ++jj) {
      int s = __shfl(myc, jj, 64);
      float sw = __shfl(myd, jj, 64);
      acc += sw * hb[(size_t)s * F + lane];
    }
  }
  Z[((size_t)g * N + d) * F + lane] = dd * acc;
}

// ---------------- aggregate-last (layer 2): out = ELU(dinv*(sum h2s) + b) ----------------
// h2s rows bf16, already pre-scaled by dinv[s] in the GEMM
template <int F>
__global__ __launch_bounds__(256) void k_agg_out(const ushort* __restrict__ Hsrc,
                                                 const int* __restrict__ rowptr,
                                                 const int* __restrict__ col,
                                                 const float* __restrict__ dinv,
                                                 const float* __restrict__ bias,
                                                 float* __restrict__ out) {
  int g, chunk;
  xcd_map(blockIdx.x, g, chunk);
  int d = chunk * 4 + (threadIdx.x >> 6);
  int lane = threadIdx.x & 63;
  const ushort* hb = Hsrc + (size_t)g * N * F;
  const int* cl = col + (size_t)g * E;
  int rs = rowptr[g * (N + 1) + d];
  int re = rowptr[g * (N + 1) + d + 1];
  float acc = bf2f(hb[(size_t)d * F + lane]);  // self loop
  for (int j0 = rs; j0 < re; j0 += 64) {
    int idx = j0 + lane;
    int myc = (idx < re) ? cl[idx] : 0;
    int nn = min(64, re - j0);
    int jj = 0;
    for (; jj + 8 <= nn; jj += 8) {
      int s[8];
#pragma unroll
      for (int k = 0; k < 8; ++k) s[k] = __shfl(myc, jj + k, 64);
      float v[8];
#pragma unroll
      for (int k = 0; k < 8; ++k) v[k] = bf2f(hb[(size_t)s[k] * F + lane]);
#pragma unroll
      for (int k = 0; k < 8; ++k) acc += v[k];
    }
    for (; jj < nn; ++jj) {
      int s = __shfl(myc, jj, 64);
      acc += bf2f(hb[(size_t)s * F + lane]);
    }
  }
  float p = acc * dinv[g * N + d] + bias[g * F + lane];
  p = p > 0.f ? p : expm1f(p);
  out[((size_t)g * N + d) * F + lane] = p;
}

extern "C" void kernel_launch(void* const* d_in, const int* in_sizes, int n_in,
                              void* d_out, int out_size, void* d_ws, size_t ws_size,
                              hipStream_t stream) {
  const float* x = (const float*)d_in[0];
  const int* ei = (const int*)d_in[1];
  const float* W1 = (const float*)d_in[2];
  const float* b1 = (const float*)d_in[3];
  const float* W2 = (const float*)d_in[4];
  const float* b2 = (const float*)d_in[5];
  float* out = (float*)d_out;

  // Workspace carve-up (~169 MB needed; rank buffer dropped vs R5)
  char* p = (char*)d_ws;
  auto alloc = [&](size_t bytes) {
    char* r = p;
    p += (bytes + 255) & ~(size_t)255;
    return r;
  };
  int* cnt = (int*)alloc(sizeof(int) * G * N);
  int* rowptr = (int*)alloc(sizeof(int) * G * (N + 1));
  int* part = (int*)alloc(sizeof(int) * G * NB);
  float* dinv = (float*)alloc(sizeof(float) * G * N);
  int* col = (int*)alloc(sizeof(int) * (size_t)G * E);             // 12.8 MB
  float* z = (float*)alloc(sizeof(float) * (size_t)G * N * FIN);   // 51.2 MB
  float* h1 = (float*)alloc(sizeof(float) * (size_t)G * N * HID);  // 102.4 MB
  ushort* h2s = (ushort*)z;  // bf16, 25.6 MB; reuses z (dead after gemm1)
  // CSR-build scratch, aliased onto later-lifetime buffers:
  ushort* H = (ushort*)z;  // per-chunk counts u16 [G][BE][N] = 12.8 MB; dead after k_off
  int* OFF = (int*)h1;     // per-chunk base offsets u32 [G][BE][N] = 25.6 MB; dead after k_fill2

  // 1. CSR build via LDS counting sort (zero device atomics)
  k_hist<<<dim3(BE, 2, G), 256, 0, stream>>>(ei, H);
  k_reduce<<<(G * N / 2 + 255) / 256, 256, 0, stream>>>(H, cnt);
  dim3 sg(NB, G);
  k_scan_partial<<<sg, 256, 0, stream>>>(cnt, part);
  k_scan_mid<<<G, 64, 0, stream>>>(part, rowptr);
  k_scan_final<<<sg, 256, 0, stream>>>(cnt, part, rowptr, dinv);
  k_off<<<(G * N / 2 + 255) / 256, 256, 0, stream>>>(H, rowptr, OFF);
  k_fill2<<<dim3(BE, 2, G), 256, 0, stream>>>(ei, OFF, col);

  // 2. layer 1: aggregate-first (fp32 gathers on x), then LDS-GEMM+bias+ELU
  k_agg_in<FIN><<<(G * N) / 4, 256, 0, stream>>>(x, rowptr, col, dinv, z);
  dim3 gg((N + 63) / 64, G);
  k_gemm_lds<FIN, HID, false, true, false>
      <<<gg, 256, 0, stream>>>(z, W1, nullptr, b1, h1);

  // 3. layer 2: transform-first 128->64 (pre-scaled, bf16 out), then aggregate
  k_gemm_lds<HID, FOUT, true, false, true>
      <<<gg, 256, 0, stream>>>(h1, W2, dinv, nullptr, h2s);
  k_agg_out<FOUT><<<(G * N) / 4, 256, 0, stream>>>(h2s, rowptr, col, dinv, b2, out);
}

// Round 3
// 619.191 us; speedup vs baseline: 1.1051x; 1.0054x over previous
//
#include <hip/hip_runtime.h>
#include <cstdint>

// Problem constants (from reference)
constexpr int G = 4, N = 50000, E = 800000;
constexpr int FIN = 64, HID = 128, FOUT = 64;
constexpr int NB = (N + 1023) / 1024;  // scan blocks per graph = 49

// Counting-sort CSR build parameters
constexpr int BE = 32;       // edge chunks per graph
constexpr int CE = E / BE;   // 25000 edges per chunk (exact)
constexpr int NHH = N / 2;   // 25000 nodes per half (u16-packed LDS = 50KB)

typedef unsigned short ushort;
typedef _Float16 f16;

__device__ __forceinline__ ushort f2h(float f) {  // v_cvt_f16_f32 (RNE)
  f16 h = (f16)f;
  return __builtin_bit_cast(ushort, h);
}
__device__ __forceinline__ float h2f(ushort u) {  // v_cvt_f32_f16
  f16 h = __builtin_bit_cast(f16, u);
  return (float)h;
}

// XCD-confined swizzle: block b -> XCD (b&7), 2 XCDs per graph.
// Requires G*N/4 = 50000 blocks; per graph 12500 chunks of 4 nodes.
__device__ __forceinline__ void xcd_map(int b, int& g, int& chunk) {
  int xcd = b & 7;
  int sub = b >> 3;  // 0..6249
  g = xcd >> 1;
  chunk = (xcd & 1) * 6250 + sub;  // 0..12499
}

// ---------------- fp32 -> fp16 conversion of x (one streamed pass) ----------------
// R7: k_agg_in was L2-miss-BW bound (FETCH 313MB @ 2.5TB/s on 819MB of fp32
// gather requests over a 12.8MB/graph working set). Halving gather bytes via
// fp16 halves both the request stream and the L2 working set (6.4MB/graph).
__global__ void k_x2h(const float4* __restrict__ X, ushort4* __restrict__ Xh, int n4) {
  int i = blockIdx.x * blockDim.x + threadIdx.x;
  if (i >= n4) return;
  float4 v = X[i];
  ushort4 o = {f2h(v.x), f2h(v.y), f2h(v.z), f2h(v.w)};
  Xh[i] = o;
}

// ---------------- CSR build: LDS counting sort (ZERO device atomics) ----------------
// R6: k_deg's 3.2M device-scope atomicAdd-with-return were memory-side RMWs
// (WRITE_SIZE 112MB, 22G atomics/s, 143us). Replaced by block-private LDS
// histograms: per (g, node-half, edge-chunk) block, u16-packed counts in
// u32[12500] = 50KB LDS. Counts <= CE=25000 so u16 never overflows and the
// packed add never carries across the halfword boundary.

__global__ __launch_bounds__(256) void k_hist(const int* __restrict__ ei,
                                              ushort* __restrict__ H) {
  __shared__ unsigned h[NHH / 2];  // 12500 words, 2 nodes/word (lo=even,hi=odd)
  int be = blockIdx.x, half = blockIdx.y, g = blockIdx.z;
  for (int i = threadIdx.x; i < NHH / 2; i += 256) h[i] = 0;
  __syncthreads();
  int h0 = half * NHH;
  const int4* dst4 = (const int4*)(ei + (size_t)g * 2 * E + E + (size_t)be * CE);
  for (int i = threadIdx.x; i < CE / 4; i += 256) {
    int4 d = dst4[i];
    int dv[4] = {d.x, d.y, d.z, d.w};
#pragma unroll
    for (int k = 0; k < 4; ++k) {
      int n = dv[k] - h0;
      if ((unsigned)n < (unsigned)NHH)
        atomicAdd(&h[n >> 1], 1u << ((n & 1) * 16));  // ds_add, no return
    }
  }
  __syncthreads();
  // H[g][be][n] as u16; write packed pairs (little-endian matches lo/hi)
  unsigned* Hw = (unsigned*)(H + ((size_t)g * BE + be) * N + h0);
  for (int i = threadIdx.x; i < NHH / 2; i += 256) Hw[i] = h[i];
}

// cnt[g][n] = sum_be H[g][be][n]  (replaces atomic counting + k_zero)
__global__ void k_reduce(const ushort* __restrict__ H, int* __restrict__ cnt) {
  int i = blockIdx.x * blockDim.x + threadIdx.x;  // over G*N/2
  if (i >= G * N / 2) return;
  int g = i / (N / 2), nw = i - g * (N / 2);
  const unsigned* Hw = (const unsigned*)(H + (size_t)g * BE * N) + nw;
  unsigned s0 = 0, s1 = 0;
#pragma unroll 8
  for (int be = 0; be < BE; ++be) {
    unsigned v = Hw[(size_t)be * (N / 2)];
    s0 += v & 0xffffu;
    s1 += v >> 16;
  }
  int2 c = {(int)s0, (int)s1};
  *(int2*)(cnt + (size_t)g * N + 2 * nw) = c;
}

// OFF[g][be][n] = rowptr[g][n] + sum_{be'<be} H[g][be'][n]
__global__ void k_off(const ushort* __restrict__ H, const int* __restrict__ rowptr,
                      int* __restrict__ OFF) {
  int i = blockIdx.x * blockDim.x + threadIdx.x;  // over G*N/2
  if (i >= G * N / 2) return;
  int g = i / (N / 2), nw = i - g * (N / 2);
  const unsigned* Hw = (const unsigned*)(H + (size_t)g * BE * N) + nw;
  // rowptr stride N+1 is odd -> scalar loads (int2 would misalign for odd g)
  int a0 = rowptr[(size_t)g * (N + 1) + 2 * nw];
  int a1 = rowptr[(size_t)g * (N + 1) + 2 * nw + 1];
  int* Ob = OFF + (size_t)g * BE * N + 2 * nw;
#pragma unroll 4
  for (int be = 0; be < BE; ++be) {
    unsigned v = Hw[(size_t)be * (N / 2)];
    int2 o = {a0, a1};
    *(int2*)(Ob + (size_t)be * N) = o;
    a0 += (int)(v & 0xffffu);
    a1 += (int)(v >> 16);
  }
}

// atomic-free-at-device fill: rank from returning LDS atomic, base from OFF
// (per-block OFF slice is 200KB -> L2-resident gather)
__global__ __launch_bounds__(256) void k_fill2(const int* __restrict__ ei,
                                               const int* __restrict__ OFF,
                                               int* __restrict__ col) {
  __shared__ unsigned rk[NHH / 2];  // packed u16 ranks, 50KB
  int be = blockIdx.x, half = blockIdx.y, g = blockIdx.z;
  int h0 = half * NHH;
  for (int i = threadIdx.x; i < NHH / 2; i += 256) rk[i] = 0;
  __syncthreads();
  const int* srcA = ei + (size_t)g * 2 * E + (size_t)be * CE;
  const int4* src4 = (const int4*)srcA;
  const int4* dst4 = (const int4*)(srcA + E);
  const int* Ob = OFF + ((size_t)g * BE + be) * N;
  int* cg = col + (size_t)g * E;
  for (int i = threadIdx.x; i < CE / 4; i += 256) {
    int4 d = dst4[i];
    int4 s = src4[i];
    int dv[4] = {d.x, d.y, d.z, d.w};
    int sv[4] = {s.x, s.y, s.z, s.w};
#pragma unroll
    for (int k = 0; k < 4; ++k) {
      int n = dv[k] - h0;
      if ((unsigned)n < (unsigned)NHH) {
        unsigned old = atomicAdd(&rk[n >> 1], 1u << ((n & 1) * 16));
        int rank = (int)((old >> ((n & 1) * 16)) & 0xffffu);
        cg[Ob[dv[k]] + rank] = sv[k];
      }
    }
  }
}

// ---- 3-kernel exclusive scan of cnt -> rowptr (per graph) ----
__global__ void k_scan_partial(const int* __restrict__ cnt, int* __restrict__ part) {
  int g = blockIdx.y, b = blockIdx.x, tid = threadIdx.x;
  int base = b * 1024 + tid * 4;
  int s = 0;
#pragma unroll
  for (int k = 0; k < 4; ++k) {
    int i = base + k;
    if (i < N) s += cnt[g * N + i];
  }
  __shared__ int sm[256];
  sm[tid] = s;
  __syncthreads();
  for (int off = 128; off > 0; off >>= 1) {
    if (tid < off) sm[tid] += sm[tid + off];
    __syncthreads();
  }
  if (tid == 0) part[g * NB + b] = sm[0];
}

__global__ void k_scan_mid(int* __restrict__ part, int* __restrict__ rowptr) {
  int g = blockIdx.x;
  if (threadIdx.x != 0) return;
  int run = 0;
  for (int b = 0; b < NB; ++b) {
    int t = part[g * NB + b];
    part[g * NB + b] = run;
    run += t;
  }
  rowptr[g * (N + 1) + N] = run;  // == E
}

// final scan + fused dinv computation
__global__ void k_scan_final(const int* __restrict__ cnt, const int* __restrict__ part,
                             int* __restrict__ rowptr, float* __restrict__ dinv) {
  int g = blockIdx.y, b = blockIdx.x, tid = threadIdx.x;
  int base = b * 1024 + tid * 4;
  int c[4];
  int s = 0;
#pragma unroll
  for (int k = 0; k < 4; ++k) {
    int i = base + k;
    c[k] = (i < N) ? cnt[g * N + i] : 0;
    s += c[k];
  }
  __shared__ int sm[256];
  sm[tid] = s;
  __syncthreads();
  for (int off = 1; off < 256; off <<= 1) {
    int v = (tid >= off) ? sm[tid - off] : 0;
    __syncthreads();
    sm[tid] += v;
    __syncthreads();
  }
  int excl = sm[tid] - s + part[g * NB + b];
#pragma unroll
  for (int k = 0; k < 4; ++k) {
    int i = base + k;
    if (i < N) {
      rowptr[g * (N + 1) + i] = excl;
      dinv[g * N + i] = rsqrtf((float)(c[k] + 1));  // +1 self loop
    }
    excl += c[k];
  }
}

// ---------------- LDS-staged GEMM: columns across waves, lane = row ----------------
// Block = 256 threads = 4 waves, covers 64 rows. X tile staged ONCE in LDS
// (padded row stride K+1 -> (lane+k)%32 bank map, 2 lanes/bank = free).
// Wave w computes columns [w*F/4, (w+1)*F/4) for all 64 rows.
// c0 forced into an SGPR via readfirstlane so the W address chain is provably
// scalar -> batched s_load through the constant cache on the scalar pipe
// (R5 bug: threadIdx-derived c0 failed divergence analysis -> per-lane
// global_load_dword, VMEM-issue bound, 230 us).
template <int K, int F, bool PRESCALE, bool BIASELU, bool OUTH>
__global__ __launch_bounds__(256) void k_gemm_lds(const float* __restrict__ X,
                                                  const float* __restrict__ W,
                                                  const float* __restrict__ dinv,
                                                  const float* __restrict__ bias,
                                                  void* __restrict__ Hout) {
  constexpr int CH = F / 4;  // columns per wave (32 or 16)
  constexpr int PK = K + 1;  // padded LDS row stride
  __shared__ float xs[64 * PK];
  int g = blockIdx.y;
  int R0 = blockIdx.x * 64;
  // stage 64 rows (coalesced global read, conflict-free LDS write)
  for (int idx = threadIdx.x; idx < 64 * K; idx += 256) {
    int r = idx / K, k = idx - r * K;
    int row = R0 + r;
    xs[r * PK + k] = (row < N) ? X[((size_t)g * N + row) * K + k] : 0.f;
  }
  __syncthreads();
  int wv = threadIdx.x >> 6;
  int lane = threadIdx.x & 63;
  int c0 = __builtin_amdgcn_readfirstlane(wv * CH);  // SGPR column base
  const float* Wg = W + (size_t)g * K * F;
  const float* xrow = &xs[lane * PK];
  float acc[CH];
#pragma unroll
  for (int c = 0; c < CH; ++c) acc[c] = 0.f;
#pragma unroll 4
  for (int k = 0; k < K; ++k) {
    float xv = xrow[k];
#pragma unroll
    for (int c = 0; c < CH; ++c)
      acc[c] = fmaf(xv, Wg[(size_t)k * F + c0 + c], acc[c]);
  }
  int row = R0 + lane;
  if (row >= N) return;
  if constexpr (PRESCALE) {
    float sc = dinv[g * N + row];
#pragma unroll
    for (int c = 0; c < CH; ++c) acc[c] *= sc;
  }
  if constexpr (BIASELU) {
#pragma unroll
    for (int c = 0; c < CH; ++c) {
      float v = acc[c] + bias[g * F + c0 + c];
      acc[c] = v > 0.f ? v : expm1f(v);
    }
  }
  if constexpr (OUTH) {  // fp16 out (R7: was bf16; fp16 = 4x finer mantissa, same bytes)
    ushort* opb = (ushort*)Hout + ((size_t)g * N + row) * F + c0;
#pragma unroll
    for (int c4 = 0; c4 < CH; c4 += 4) {
      ushort4 o = {f2h(acc[c4]), f2h(acc[c4 + 1]), f2h(acc[c4 + 2]),
                   f2h(acc[c4 + 3])};
      *(ushort4*)(opb + c4) = o;
    }
  } else {
    float* op = (float*)Hout + ((size_t)g * N + row) * F + c0;
#pragma unroll
    for (int c4 = 0; c4 < CH; c4 += 4) {
      float4 o = {acc[c4], acc[c4 + 1], acc[c4 + 2], acc[c4 + 3]};
      *(float4*)(op + c4) = o;
    }
  }
}

// ---------------- aggregate-first (layer 1): Z = D^-1/2 (A+I) D^-1/2 X ----------------
// one wave per dst node; F = 64 (1 fp16/lane = 128B coalesced row gather);
// dinv[s] folded in via shfl broadcast
template <int F>
__global__ __launch_bounds__(256) void k_agg_in(const ushort* __restrict__ Xh,
                                                const int* __restrict__ rowptr,
                                                const int* __restrict__ col,
                                                const float* __restrict__ dinv,
                                                float* __restrict__ Z) {
  int g, chunk;
  xcd_map(blockIdx.x, g, chunk);
  int d = chunk * 4 + (threadIdx.x >> 6);
  int lane = threadIdx.x & 63;
  const ushort* hb = Xh + (size_t)g * N * F;
  const float* dv = dinv + g * N;
  const int* cl = col + (size_t)g * E;
  int rs = rowptr[g * (N + 1) + d];
  int re = rowptr[g * (N + 1) + d + 1];
  float dd = dv[d];
  float acc = dd * h2f(hb[(size_t)d * F + lane]);  // self loop
  for (int j0 = rs; j0 < re; j0 += 64) {
    int idx = j0 + lane;
    int myc = (idx < re) ? cl[idx] : 0;
    float myd = (idx < re) ? dv[myc] : 0.f;
    int nn = min(64, re - j0);
    int jj = 0;
    for (; jj + 8 <= nn; jj += 8) {
      int s[8];
      float sw[8];
#pragma unroll
      for (int k = 0; k < 8; ++k) {
        s[k] = __shfl(myc, jj + k, 64);
        sw[k] = __shfl(myd, jj + k, 64);
      }
      float v[8];
#pragma unroll
      for (int k = 0; k < 8; ++k) v[k] = h2f(hb[(size_t)s[k] * F + lane]);
#pragma unroll
      for (int k = 0; k < 8; ++k) acc += sw[k] * v[k];
    }
    for (; jj < nn; ++jj) {
      int s = __shfl(myc, jj, 64);
      float sw = __shfl(myd, jj, 64);
      acc += sw * h2f(hb[(size_t)s * F + lane]);
    }
  }
  Z[((size_t)g * N + d) * F + lane] = dd * acc;
}

// ---------------- aggregate-last (layer 2): out = ELU(dinv*(sum h2s) + b) ----------------
// h2s rows fp16, already pre-scaled by dinv[s] in the GEMM
template <int F>
__global__ __launch_bounds__(256) void k_agg_out(const ushort* __restrict__ Hsrc,
                                                 const int* __restrict__ rowptr,
                                                 const int* __restrict__ col,
                                                 const float* __restrict__ dinv,
                                                 const float* __restrict__ bias,
                                                 float* __restrict__ out) {
  int g, chunk;
  xcd_map(blockIdx.x, g, chunk);
  int d = chunk * 4 + (threadIdx.x >> 6);
  int lane = threadIdx.x & 63;
  const ushort* hb = Hsrc + (size_t)g * N * F;
  const int* cl = col + (size_t)g * E;
  int rs = rowptr[g * (N + 1) + d];
  int re = rowptr[g * (N + 1) + d + 1];
  float acc = h2f(hb[(size_t)d * F + lane]);  // self loop
  for (int j0 = rs; j0 < re; j0 += 64) {
    int idx = j0 + lane;
    int myc = (idx < re) ? cl[idx] : 0;
    int nn = min(64, re - j0);
    int jj = 0;
    for (; jj + 8 <= nn; jj += 8) {
      int s[8];
#pragma unroll
      for (int k = 0; k < 8; ++k) s[k] = __shfl(myc, jj + k, 64);
      float v[8];
#pragma unroll
      for (int k = 0; k < 8; ++k) v[k] = h2f(hb[(size_t)s[k] * F + lane]);
#pragma unroll
      for (int k = 0; k < 8; ++k) acc += v[k];
    }
    for (; jj < nn; ++jj) {
      int s = __shfl(myc, jj, 64);
      acc += h2f(hb[(size_t)s * F + lane]);
    }
  }
  float p = acc * dinv[g * N + d] + bias[g * F + lane];
  p = p > 0.f ? p : expm1f(p);
  out[((size_t)g * N + d) * F + lane] = p;
}

extern "C" void kernel_launch(void* const* d_in, const int* in_sizes, int n_in,
                              void* d_out, int out_size, void* d_ws, size_t ws_size,
                              hipStream_t stream) {
  const float* x = (const float*)d_in[0];
  const int* ei = (const int*)d_in[1];
  const float* W1 = (const float*)d_in[2];
  const float* b1 = (const float*)d_in[3];
  const float* W2 = (const float*)d_in[4];
  const float* b2 = (const float*)d_in[5];
  float* out = (float*)d_out;

  // Workspace carve-up (~169 MB; all CSR/fp16 scratch aliased onto z/h1)
  char* p = (char*)d_ws;
  auto alloc = [&](size_t bytes) {
    char* r = p;
    p += (bytes + 255) & ~(size_t)255;
    return r;
  };
  int* cnt = (int*)alloc(sizeof(int) * G * N);
  int* rowptr = (int*)alloc(sizeof(int) * G * (N + 1));
  int* part = (int*)alloc(sizeof(int) * G * NB);
  float* dinv = (float*)alloc(sizeof(float) * G * N);
  int* col = (int*)alloc(sizeof(int) * (size_t)G * E);             // 12.8 MB
  float* z = (float*)alloc(sizeof(float) * (size_t)G * N * FIN);   // 51.2 MB
  float* h1 = (float*)alloc(sizeof(float) * (size_t)G * N * HID);  // 102.4 MB
  ushort* h2s = (ushort*)z;  // fp16, 25.6 MB; reuses z (dead after gemm1)
  // CSR-build + fp16-x scratch, aliased onto later-lifetime buffers:
  ushort* H = (ushort*)z;    // per-chunk counts u16 [G][BE][N] = 12.8 MB; dead after k_off
  int* OFF = (int*)h1;       // per-chunk base offsets [G][BE][N] = 25.6 MB; dead after k_fill2
  // xh at h1+32MB: disjoint from OFF (first 25.6 MB); h1 proper written only
  // after k_agg_in (stream-serial), by which point xh is dead.
  ushort* xh = (ushort*)((char*)h1 + ((size_t)32 << 20));  // fp16 x, 25.6 MB

  // 0. x -> fp16 (halves k_agg_in gather bytes AND its L2 working set)
  k_x2h<<<(G * N * FIN / 4 + 255) / 256, 256, 0, stream>>>((const float4*)x,
                                                           (ushort4*)xh, G * N * FIN / 4);

  // 1. CSR build via LDS counting sort (zero device atomics)
  k_hist<<<dim3(BE, 2, G), 256, 0, stream>>>(ei, H);
  k_reduce<<<(G * N / 2 + 255) / 256, 256, 0, stream>>>(H, cnt);
  dim3 sg(NB, G);
  k_scan_partial<<<sg, 256, 0, stream>>>(cnt, part);
  k_scan_mid<<<G, 64, 0, stream>>>(part, rowptr);
  k_scan_final<<<sg, 256, 0, stream>>>(cnt, part, rowptr, dinv);
  k_off<<<(G * N / 2 + 255) / 256, 256, 0, stream>>>(H, rowptr, OFF);
  k_fill2<<<dim3(BE, 2, G), 256, 0, stream>>>(ei, OFF, col);

  // 2. layer 1: aggregate-first (fp16 gathers on x), then LDS-GEMM+bias+ELU
  k_agg_in<FIN><<<(G * N) / 4, 256, 0, stream>>>(xh, rowptr, col, dinv, z);
  dim3 gg((N + 63) / 64, G);
  k_gemm_lds<FIN, HID, false, true, false>
      <<<gg, 256, 0, stream>>>(z, W1, nullptr, b1, h1);

  // 3. layer 2: transform-first 128->64 (pre-scaled, fp16 out), then aggregate
  k_gemm_lds<HID, FOUT, true, false, true>
      <<<gg, 256, 0, stream>>>(h1, W2, dinv, nullptr, h2s);
  k_agg_out<FOUT><<<(G * N) / 4, 256, 0, stream>>>(h2s, rowptr, col, dinv, b2, out);
}

// Round 4
// 544.502 us; speedup vs baseline: 1.2567x; 1.1372x over previous
//
#include <hip/hip_runtime.h>
#include <cstdint>

// Problem constants (from reference)
constexpr int G = 4, N = 50000, E = 800000;
constexpr int FIN = 64, HID = 128, FOUT = 64;
constexpr int NB = (N + 1023) / 1024;  // scan blocks per graph = 49

// Radix CSR-build parameters (R9)
constexpr int PB = 64;               // partition blocks per graph
constexpr int CP = E / PB;           // 12500 edges per partition chunk (exact)
constexpr int NBK = (N + 255) / 256; // 196 dst-buckets of 256 nodes

typedef unsigned short ushort;
typedef _Float16 f16;

__device__ __forceinline__ ushort f2h(float f) {  // v_cvt_f16_f32 (RNE)
  f16 h = (f16)f;
  return __builtin_bit_cast(ushort, h);
}
__device__ __forceinline__ float h2f(ushort u) {  // v_cvt_f32_f16
  f16 h = __builtin_bit_cast(f16, u);
  return (float)h;
}

// XCD-confined swizzle: block b -> XCD (b&7), 2 XCDs per graph.
// Requires G*N/4 = 50000 blocks; per graph 12500 chunks of 4 nodes.
__device__ __forceinline__ void xcd_map(int b, int& g, int& chunk) {
  int xcd = b & 7;
  int sub = b >> 3;  // 0..6249
  g = xcd >> 1;
  chunk = (xcd & 1) * 6250 + sub;  // 0..12499
}

// ---------------- fp32 -> fp16 conversion of x (one streamed pass) ----------------
// R7: k_agg_in was L2-miss-BW bound; fp16 halves gather bytes + L2 working set.
__global__ void k_x2h(const float4* __restrict__ X, ushort4* __restrict__ Xh, int n4) {
  int i = blockIdx.x * blockDim.x + threadIdx.x;
  if (i >= n4) return;
  float4 v = X[i];
  ushort4 o = {f2h(v.x), f2h(v.y), f2h(v.z), f2h(v.w)};
  Xh[i] = o;
}

// ---------------- CSR build: two-pass radix partition by dst (R9) ----------------
// R8 post-mortem: k_fill2's 3.2M scattered 4B col stores ran at 27G/s with 8x
// write amplification (WRITE 105MB vs 12.8MB ideal) -- same memory-side RMW
// disease as the old k_deg atomics. Scattered SUB-LINE stores cost like atomics.
// Fix: every global write made (near-)line-contiguous.
//   P1: partition edges into NBK=196 dst-buckets (256 nodes each); pairs packed
//       as src | (dst&255)<<16 (src < 65536). Per-(block,bucket) segments are
//       contiguous (~256B) -> line-local writes.
//   P2a (k_bcnt): per-bucket 1KB LDS histogram -> cnt (contiguous). Replaces
//       the 50KB-LDS k_hist + k_reduce entirely.
//   P2b (k_place): per-bucket block ranks pairs in LDS, writes col within a
//       ~16KB window -> lines fully dirtied in L2 before writeback.

// PH[g][k][pb]: bucket-k count of partition chunk pb
__global__ __launch_bounds__(256) void k_phist(const int* __restrict__ ei,
                                               int* __restrict__ PH) {
  __shared__ int h[NBK];
  int pb = blockIdx.x, g = blockIdx.y;
  for (int i = threadIdx.x; i < NBK; i += 256) h[i] = 0;
  __syncthreads();
  const int4* dst4 = (const int4*)(ei + (size_t)g * 2 * E + E + (size_t)pb * CP);
  for (int i = threadIdx.x; i < CP / 4; i += 256) {
    int4 d = dst4[i];
    atomicAdd(&h[d.x >> 8], 1);
    atomicAdd(&h[d.y >> 8], 1);
    atomicAdd(&h[d.z >> 8], 1);
    atomicAdd(&h[d.w >> 8], 1);
  }
  __syncthreads();
  for (int i = threadIdx.x; i < NBK; i += 256)
    PH[((size_t)g * NBK + i) * PB + pb] = h[i];
}

// scan PH -> POFF[g][k][pb] (segment base in pairs) and BB[g][k] (bucket base)
__global__ void k_pscan(const int* __restrict__ PH, int* __restrict__ POFF,
                        int* __restrict__ BB) {
  int g = blockIdx.x, k = threadIdx.x;  // 256 threads, k < NBK active
  int tot = 0;
  if (k < NBK) {
#pragma unroll 8
    for (int pb = 0; pb < PB; ++pb) tot += PH[((size_t)g * NBK + k) * PB + pb];
  }
  __shared__ int sm[256];
  sm[k] = tot;
  __syncthreads();
  for (int off = 1; off < 256; off <<= 1) {
    int v = (k >= off) ? sm[k - off] : 0;
    __syncthreads();
    sm[k] += v;
    __syncthreads();
  }
  int excl = sm[k] - tot;
  if (k < NBK) {
    BB[g * (NBK + 1) + k] = excl;
    if (k == NBK - 1) BB[g * (NBK + 1) + NBK] = excl + tot;  // == E
    int run = excl;
#pragma unroll 8
    for (int pb = 0; pb < PB; ++pb) {
      POFF[((size_t)g * NBK + k) * PB + pb] = run;
      run += PH[((size_t)g * NBK + k) * PB + pb];
    }
  }
}

// partition: write packed (src, dst&255) into bucket-major pairs array
__global__ __launch_bounds__(256) void k_part(const int* __restrict__ ei,
                                              const int* __restrict__ POFF,
                                              unsigned* __restrict__ pairs) {
  __shared__ int off[NBK];
  __shared__ int rk[NBK];
  int pb = blockIdx.x, g = blockIdx.y;
  for (int i = threadIdx.x; i < NBK; i += 256) {
    off[i] = POFF[((size_t)g * NBK + i) * PB + pb];
    rk[i] = 0;
  }
  __syncthreads();
  const int* base = ei + (size_t)g * 2 * E + (size_t)pb * CP;
  const int4* s4 = (const int4*)base;
  const int4* d4 = (const int4*)(base + E);
  unsigned* pg = pairs + (size_t)g * E;
  for (int i = threadIdx.x; i < CP / 4; i += 256) {
    int4 s = s4[i], d = d4[i];
    int sv[4] = {s.x, s.y, s.z, s.w};
    int dv[4] = {d.x, d.y, d.z, d.w};
#pragma unroll
    for (int k = 0; k < 4; ++k) {
      int b = dv[k] >> 8;
      int r = atomicAdd(&rk[b], 1);
      pg[off[b] + r] = (unsigned)sv[k] | ((unsigned)(dv[k] & 255) << 16);
    }
  }
}

// per-bucket exact node counts -> cnt (contiguous writes)
__global__ __launch_bounds__(256) void k_bcnt(const unsigned* __restrict__ pairs,
                                              const int* __restrict__ BB,
                                              int* __restrict__ cnt) {
  __shared__ int h[256];
  int k = blockIdx.x, g = blockIdx.y;
  h[threadIdx.x] = 0;
  __syncthreads();
  int lo = BB[g * (NBK + 1) + k], hi = BB[g * (NBK + 1) + k + 1];
  const unsigned* pg = pairs + (size_t)g * E;
  for (int i = lo + (int)threadIdx.x; i < hi; i += 256)
    atomicAdd(&h[(pg[i] >> 16) & 255], 1);
  __syncthreads();
  int n0 = k << 8;
  int nn = min(256, N - n0);
  if ((int)threadIdx.x < nn) cnt[g * N + n0 + threadIdx.x] = h[threadIdx.x];
}

// place srcs into col; scatter confined to the bucket's ~16KB col window
__global__ __launch_bounds__(256) void k_place(const unsigned* __restrict__ pairs,
                                               const int* __restrict__ BB,
                                               const int* __restrict__ rowptr,
                                               int* __restrict__ col) {
  __shared__ int rp[256];
  __shared__ int rk[256];
  int k = blockIdx.x, g = blockIdx.y;
  int n0 = k << 8;
  int nn = min(256, N - n0);
  if ((int)threadIdx.x < nn) rp[threadIdx.x] = rowptr[g * (N + 1) + n0 + threadIdx.x];
  rk[threadIdx.x] = 0;
  __syncthreads();
  int lo = BB[g * (NBK + 1) + k], hi = BB[g * (NBK + 1) + k + 1];
  const unsigned* pg = pairs + (size_t)g * E;
  int* cg = col + (size_t)g * E;
  for (int i = lo + (int)threadIdx.x; i < hi; i += 256) {
    unsigned p = pg[i];
    int dl = (p >> 16) & 255;
    int r = atomicAdd(&rk[dl], 1);
    cg[rp[dl] + r] = (int)(p & 0xffffu);
  }
}

// ---- 3-kernel exclusive scan of cnt -> rowptr (per graph) ----
__global__ void k_scan_partial(const int* __restrict__ cnt, int* __restrict__ part) {
  int g = blockIdx.y, b = blockIdx.x, tid = threadIdx.x;
  int base = b * 1024 + tid * 4;
  int s = 0;
#pragma unroll
  for (int k = 0; k < 4; ++k) {
    int i = base + k;
    if (i < N) s += cnt[g * N + i];
  }
  __shared__ int sm[256];
  sm[tid] = s;
  __syncthreads();
  for (int off = 128; off > 0; off >>= 1) {
    if (tid < off) sm[tid] += sm[tid + off];
    __syncthreads();
  }
  if (tid == 0) part[g * NB + b] = sm[0];
}

__global__ void k_scan_mid(int* __restrict__ part, int* __restrict__ rowptr) {
  int g = blockIdx.x;
  if (threadIdx.x != 0) return;
  int run = 0;
  for (int b = 0; b < NB; ++b) {
    int t = part[g * NB + b];
    part[g * NB + b] = run;
    run += t;
  }
  rowptr[g * (N + 1) + N] = run;  // == E
}

// final scan + fused dinv computation
__global__ void k_scan_final(const int* __restrict__ cnt, const int* __restrict__ part,
                             int* __restrict__ rowptr, float* __restrict__ dinv) {
  int g = blockIdx.y, b = blockIdx.x, tid = threadIdx.x;
  int base = b * 1024 + tid * 4;
  int c[4];
  int s = 0;
#pragma unroll
  for (int k = 0; k < 4; ++k) {
    int i = base + k;
    c[k] = (i < N) ? cnt[g * N + i] : 0;
    s += c[k];
  }
  __shared__ int sm[256];
  sm[tid] = s;
  __syncthreads();
  for (int off = 1; off < 256; off <<= 1) {
    int v = (tid >= off) ? sm[tid - off] : 0;
    __syncthreads();
    sm[tid] += v;
    __syncthreads();
  }
  int excl = sm[tid] - s + part[g * NB + b];
#pragma unroll
  for (int k = 0; k < 4; ++k) {
    int i = base + k;
    if (i < N) {
      rowptr[g * (N + 1) + i] = excl;
      dinv[g * N + i] = rsqrtf((float)(c[k] + 1));  // +1 self loop
    }
    excl += c[k];
  }
}

// ---------------- LDS-staged GEMM: columns across waves, lane = row ----------------
// Block = 256 threads = 4 waves, covers 64 rows. X tile staged ONCE in LDS
// (padded row stride K+1 -> (lane+k)%32 bank map, 2 lanes/bank = free).
// Wave w computes columns [w*F/4, (w+1)*F/4) for all 64 rows.
// c0 forced into an SGPR via readfirstlane so the W address chain is provably
// scalar -> batched s_load through the constant cache on the scalar pipe
// (R5 bug: threadIdx-derived c0 failed divergence analysis -> per-lane
// global_load_dword, VMEM-issue bound, 230 us).
template <int K, int F, bool PRESCALE, bool BIASELU, bool OUTH>
__global__ __launch_bounds__(256) void k_gemm_lds(const float* __restrict__ X,
                                                  const float* __restrict__ W,
                                                  const float* __restrict__ dinv,
                                                  const float* __restrict__ bias,
                                                  void* __restrict__ Hout) {
  constexpr int CH = F / 4;  // columns per wave (32 or 16)
  constexpr int PK = K + 1;  // padded LDS row stride
  __shared__ float xs[64 * PK];
  int g = blockIdx.y;
  int R0 = blockIdx.x * 64;
  // stage 64 rows (coalesced global read, conflict-free LDS write)
  for (int idx = threadIdx.x; idx < 64 * K; idx += 256) {
    int r = idx / K, k = idx - r * K;
    int row = R0 + r;
    xs[r * PK + k] = (row < N) ? X[((size_t)g * N + row) * K + k] : 0.f;
  }
  __syncthreads();
  int wv = threadIdx.x >> 6;
  int lane = threadIdx.x & 63;
  int c0 = __builtin_amdgcn_readfirstlane(wv * CH);  // SGPR column base
  const float* Wg = W + (size_t)g * K * F;
  const float* xrow = &xs[lane * PK];
  float acc[CH];
#pragma unroll
  for (int c = 0; c < CH; ++c) acc[c] = 0.f;
#pragma unroll 4
  for (int k = 0; k < K; ++k) {
    float xv = xrow[k];
#pragma unroll
    for (int c = 0; c < CH; ++c)
      acc[c] = fmaf(xv, Wg[(size_t)k * F + c0 + c], acc[c]);
  }
  int row = R0 + lane;
  if (row >= N) return;
  if constexpr (PRESCALE) {
    float sc = dinv[g * N + row];
#pragma unroll
    for (int c = 0; c < CH; ++c) acc[c] *= sc;
  }
  if constexpr (BIASELU) {
#pragma unroll
    for (int c = 0; c < CH; ++c) {
      float v = acc[c] + bias[g * F + c0 + c];
      acc[c] = v > 0.f ? v : expm1f(v);
    }
  }
  if constexpr (OUTH) {  // fp16 out (4x finer mantissa than bf16, same bytes)
    ushort* opb = (ushort*)Hout + ((size_t)g * N + row) * F + c0;
#pragma unroll
    for (int c4 = 0; c4 < CH; c4 += 4) {
      ushort4 o = {f2h(acc[c4]), f2h(acc[c4 + 1]), f2h(acc[c4 + 2]),
                   f2h(acc[c4 + 3])};
      *(ushort4*)(opb + c4) = o;
    }
  } else {
    float* op = (float*)Hout + ((size_t)g * N + row) * F + c0;
#pragma unroll
    for (int c4 = 0; c4 < CH; c4 += 4) {
      float4 o = {acc[c4], acc[c4 + 1], acc[c4 + 2], acc[c4 + 3]};
      *(float4*)(op + c4) = o;
    }
  }
}

// ---------------- aggregate-first (layer 1): Z = D^-1/2 (A+I) D^-1/2 X ----------------
// one wave per dst node; F = 64 (1 fp16/lane = 128B coalesced row gather);
// dinv[s] folded in via shfl broadcast
template <int F>
__global__ __launch_bounds__(256) void k_agg_in(const ushort* __restrict__ Xh,
                                                const int* __restrict__ rowptr,
                                                const int* __restrict__ col,
                                                const float* __restrict__ dinv,
                                                float* __restrict__ Z) {
  int g, chunk;
  xcd_map(blockIdx.x, g, chunk);
  int d = chunk * 4 + (threadIdx.x >> 6);
  int lane = threadIdx.x & 63;
  const ushort* hb = Xh + (size_t)g * N * F;
  const float* dv = dinv + g * N;
  const int* cl = col + (size_t)g * E;
  int rs = rowptr[g * (N + 1) + d];
  int re = rowptr[g * (N + 1) + d + 1];
  float dd = dv[d];
  float acc = dd * h2f(hb[(size_t)d * F + lane]);  // self loop
  for (int j0 = rs; j0 < re; j0 += 64) {
    int idx = j0 + lane;
    int myc = (idx < re) ? cl[idx] : 0;
    float myd = (idx < re) ? dv[myc] : 0.f;
    int nn = min(64, re - j0);
    int jj = 0;
    for (; jj + 8 <= nn; jj += 8) {
      int s[8];
      float sw[8];
#pragma unroll
      for (int k = 0; k < 8; ++k) {
        s[k] = __shfl(myc, jj + k, 64);
        sw[k] = __shfl(myd, jj + k, 64);
      }
      float v[8];
#pragma unroll
      for (int k = 0; k < 8; ++k) v[k] = h2f(hb[(size_t)s[k] * F + lane]);
#pragma unroll
      for (int k = 0; k < 8; ++k) acc += sw[k] * v[k];
    }
    for (; jj < nn; ++jj) {
      int s = __shfl(myc, jj, 64);
      float sw = __shfl(myd, jj, 64);
      acc += sw * h2f(hb[(size_t)s * F + lane]);
    }
  }
  Z[((size_t)g * N + d) * F + lane] = dd * acc;
}

// ---------------- aggregate-last (layer 2): out = ELU(dinv*(sum h2s) + b) ----------------
// h2s rows fp16, already pre-scaled by dinv[s] in the GEMM
template <int F>
__global__ __launch_bounds__(256) void k_agg_out(const ushort* __restrict__ Hsrc,
                                                 const int* __restrict__ rowptr,
                                                 const int* __restrict__ col,
                                                 const float* __restrict__ dinv,
                                                 const float* __restrict__ bias,
                                                 float* __restrict__ out) {
  int g, chunk;
  xcd_map(blockIdx.x, g, chunk);
  int d = chunk * 4 + (threadIdx.x >> 6);
  int lane = threadIdx.x & 63;
  const ushort* hb = Hsrc + (size_t)g * N * F;
  const int* cl = col + (size_t)g * E;
  int rs = rowptr[g * (N + 1) + d];
  int re = rowptr[g * (N + 1) + d + 1];
  float acc = h2f(hb[(size_t)d * F + lane]);  // self loop
  for (int j0 = rs; j0 < re; j0 += 64) {
    int idx = j0 + lane;
    int myc = (idx < re) ? cl[idx] : 0;
    int nn = min(64, re - j0);
    int jj = 0;
    for (; jj + 8 <= nn; jj += 8) {
      int s[8];
#pragma unroll
      for (int k = 0; k < 8; ++k) s[k] = __shfl(myc, jj + k, 64);
      float v[8];
#pragma unroll
      for (int k = 0; k < 8; ++k) v[k] = h2f(hb[(size_t)s[k] * F + lane]);
#pragma unroll
      for (int k = 0; k < 8; ++k) acc += v[k];
    }
    for (; jj < nn; ++jj) {
      int s = __shfl(myc, jj, 64);
      acc += h2f(hb[(size_t)s * F + lane]);
    }
  }
  float p = acc * dinv[g * N + d] + bias[g * F + lane];
  p = p > 0.f ? p : expm1f(p);
  out[((size_t)g * N + d) * F + lane] = p;
}

extern "C" void kernel_launch(void* const* d_in, const int* in_sizes, int n_in,
                              void* d_out, int out_size, void* d_ws, size_t ws_size,
                              hipStream_t stream) {
  const float* x = (const float*)d_in[0];
  const int* ei = (const int*)d_in[1];
  const float* W1 = (const float*)d_in[2];
  const float* b1 = (const float*)d_in[3];
  const float* W2 = (const float*)d_in[4];
  const float* b2 = (const float*)d_in[5];
  float* out = (float*)d_out;

  // Workspace carve-up (~169 MB; all radix/fp16 scratch aliased onto h1)
  char* p = (char*)d_ws;
  auto alloc = [&](size_t bytes) {
    char* r = p;
    p += (bytes + 255) & ~(size_t)255;
    return r;
  };
  int* cnt = (int*)alloc(sizeof(int) * G * N);
  int* rowptr = (int*)alloc(sizeof(int) * G * (N + 1));
  int* part = (int*)alloc(sizeof(int) * G * NB);
  float* dinv = (float*)alloc(sizeof(float) * G * N);
  int* col = (int*)alloc(sizeof(int) * (size_t)G * E);             // 12.8 MB
  float* z = (float*)alloc(sizeof(float) * (size_t)G * N * FIN);   // 51.2 MB
  float* h1 = (float*)alloc(sizeof(float) * (size_t)G * N * HID);  // 102.4 MB
  ushort* h2s = (ushort*)z;  // fp16, 25.6 MB; reuses z (dead after gemm1)
  // Radix + fp16-x scratch aliased into h1 (all dead before gemm1 writes h1):
  unsigned* pairs = (unsigned*)h1;                         // 12.8 MB
  int* PH = (int*)((char*)h1 + ((size_t)13 << 20));        // G*NBK*PB*4 = 200KB
  int* POFF = (int*)((char*)h1 + ((size_t)14 << 20));      // 200KB
  int* BB = (int*)((char*)h1 + ((size_t)15 << 20));        // G*(NBK+1)*4 = 3.2KB
  ushort* xh = (ushort*)((char*)h1 + ((size_t)32 << 20));  // fp16 x, 25.6 MB

  // 0. x -> fp16 (halves k_agg_in gather bytes AND its L2 working set)
  k_x2h<<<(G * N * FIN / 4 + 255) / 256, 256, 0, stream>>>((const float4*)x,
                                                           (ushort4*)xh, G * N * FIN / 4);

  // 1. CSR build via two-pass radix partition (line-contiguous writes only)
  k_phist<<<dim3(PB, G), 256, 0, stream>>>(ei, PH);
  k_pscan<<<G, 256, 0, stream>>>(PH, POFF, BB);
  k_part<<<dim3(PB, G), 256, 0, stream>>>(ei, POFF, pairs);
  k_bcnt<<<dim3(NBK, G), 256, 0, stream>>>(pairs, BB, cnt);
  dim3 sg(NB, G);
  k_scan_partial<<<sg, 256, 0, stream>>>(cnt, part);
  k_scan_mid<<<G, 64, 0, stream>>>(part, rowptr);
  k_scan_final<<<sg, 256, 0, stream>>>(cnt, part, rowptr, dinv);
  k_place<<<dim3(NBK, G), 256, 0, stream>>>(pairs, BB, rowptr, col);

  // 2. layer 1: aggregate-first (fp16 gathers on x), then LDS-GEMM+bias+ELU
  k_agg_in<FIN><<<(G * N) / 4, 256, 0, stream>>>(xh, rowptr, col, dinv, z);
  dim3 gg((N + 63) / 64, G);
  k_gemm_lds<FIN, HID, false, true, false>
      <<<gg, 256, 0, stream>>>(z, W1, nullptr, b1, h1);

  // 3. layer 2: transform-first 128->64 (pre-scaled, fp16 out), then aggregate
  k_gemm_lds<HID, FOUT, true, false, true>
      <<<gg, 256, 0, stream>>>(h1, W2, dinv, nullptr, h2s);
  k_agg_out<FOUT><<<(G * N) / 4, 256, 0, stream>>>(h2s, rowptr, col, dinv, b2, out);
}

// Round 6
// 525.210 us; speedup vs baseline: 1.3029x; 1.0367x over previous
//
#include <hip/hip_runtime.h>
#include <cstdint>

// Problem constants (from reference)
constexpr int G = 4, N = 50000, E = 800000;
constexpr int FIN = 64, HID = 128, FOUT = 64;
constexpr int NB = (N + 1023) / 1024;  // scan blocks per graph = 49

// Radix CSR-build parameters (R9)
constexpr int PB = 64;               // partition blocks per graph
constexpr int CP = E / PB;           // 12500 edges per partition chunk (exact)
constexpr int NBK = (N + 255) / 256; // 196 dst-buckets of 256 nodes

typedef unsigned short ushort;
typedef _Float16 f16;

__device__ __forceinline__ ushort f2h(float f) {  // v_cvt_f16_f32 (RNE)
  f16 h = (f16)f;
  return __builtin_bit_cast(ushort, h);
}
__device__ __forceinline__ float h2f(ushort u) {  // v_cvt_f32_f16
  f16 h = __builtin_bit_cast(f16, u);
  return (float)h;
}

// XCD-confined swizzle: block b -> XCD (b&7), 2 XCDs per graph.
// Requires G*N/4 = 50000 blocks; per graph 12500 chunks of 4 nodes.
__device__ __forceinline__ void xcd_map(int b, int& g, int& chunk) {
  int xcd = b & 7;
  int sub = b >> 3;  // 0..6249
  g = xcd >> 1;
  chunk = (xcd & 1) * 6250 + sub;  // 0..12499
}

// ---------------- fp32 -> fp16 conversion of x, PRE-SCALED by dinv ----------------
// R7: fp16 halves gather bytes + L2 working set. R10: also fold dinv[s] into
// the stored row (xh[s] = dinv[s]*x[s]) so the aggregation needs NO per-edge
// dinv gather / shfl -- Z = dinv[d] * sum_{s in N(d)+self} xh[s].
// Runs AFTER the CSR scans (needs dinv).
__global__ void k_x2h(const float4* __restrict__ X, const float* __restrict__ dinv,
                      ushort4* __restrict__ Xh, int n4) {
  int i = blockIdx.x * blockDim.x + threadIdx.x;
  if (i >= n4) return;
  float sc = dinv[i >> 4];  // 16 float4 per 64-wide row; same dinv for all 16
  float4 v = X[i];
  ushort4 o = {f2h(sc * v.x), f2h(sc * v.y), f2h(sc * v.z), f2h(sc * v.w)};
  Xh[i] = o;
}

// ---------------- CSR build: two-pass radix partition by dst (R9) ----------------
// R8 post-mortem: scattered SUB-LINE stores cost like atomics (8x write amp).
// All global writes made (near-)line-contiguous via 196-bucket dst partition.

// PH[g][k][pb]: bucket-k count of partition chunk pb
__global__ __launch_bounds__(256) void k_phist(const int* __restrict__ ei,
                                               int* __restrict__ PH) {
  __shared__ int h[NBK];
  int pb = blockIdx.x, g = blockIdx.y;
  for (int i = threadIdx.x; i < NBK; i += 256) h[i] = 0;
  __syncthreads();
  const int4* dst4 = (const int4*)(ei + (size_t)g * 2 * E + E + (size_t)pb * CP);
  for (int i = threadIdx.x; i < CP / 4; i += 256) {
    int4 d = dst4[i];
    atomicAdd(&h[d.x >> 8], 1);
    atomicAdd(&h[d.y >> 8], 1);
    atomicAdd(&h[d.z >> 8], 1);
    atomicAdd(&h[d.w >> 8], 1);
  }
  __syncthreads();
  for (int i = threadIdx.x; i < NBK; i += 256)
    PH[((size_t)g * NBK + i) * PB + pb] = h[i];
}

// scan PH -> POFF[g][k][pb] (segment base in pairs) and BB[g][k] (bucket base)
__global__ void k_pscan(const int* __restrict__ PH, int* __restrict__ POFF,
                        int* __restrict__ BB) {
  int g = blockIdx.x, k = threadIdx.x;  // 256 threads, k < NBK active
  int tot = 0;
  if (k < NBK) {
#pragma unroll 8
    for (int pb = 0; pb < PB; ++pb) tot += PH[((size_t)g * NBK + k) * PB + pb];
  }
  __shared__ int sm[256];
  sm[k] = tot;
  __syncthreads();
  for (int off = 1; off < 256; off <<= 1) {
    int v = (k >= off) ? sm[k - off] : 0;
    __syncthreads();
    sm[k] += v;
    __syncthreads();
  }
  int excl = sm[k] - tot;
  if (k < NBK) {
    BB[g * (NBK + 1) + k] = excl;
    if (k == NBK - 1) BB[g * (NBK + 1) + NBK] = excl + tot;  // == E
    int run = excl;
#pragma unroll 8
    for (int pb = 0; pb < PB; ++pb) {
      POFF[((size_t)g * NBK + k) * PB + pb] = run;
      run += PH[((size_t)g * NBK + k) * PB + pb];
    }
  }
}

// partition: write packed (src, dst&255) into bucket-major pairs array
__global__ __launch_bounds__(256) void k_part(const int* __restrict__ ei,
                                              const int* __restrict__ POFF,
                                              unsigned* __restrict__ pairs) {
  __shared__ int off[NBK];
  __shared__ int rk[NBK];
  int pb = blockIdx.x, g = blockIdx.y;
  for (int i = threadIdx.x; i < NBK; i += 256) {
    off[i] = POFF[((size_t)g * NBK + i) * PB + pb];
    rk[i] = 0;
  }
  __syncthreads();
  const int* base = ei + (size_t)g * 2 * E + (size_t)pb * CP;
  const int4* s4 = (const int4*)base;
  const int4* d4 = (const int4*)(base + E);
  unsigned* pg = pairs + (size_t)g * E;
  for (int i = threadIdx.x; i < CP / 4; i += 256) {
    int4 s = s4[i], d = d4[i];
    int sv[4] = {s.x, s.y, s.z, s.w};
    int dv[4] = {d.x, d.y, d.z, d.w};
#pragma unroll
    for (int k = 0; k < 4; ++k) {
      int b = dv[k] >> 8;
      int r = atomicAdd(&rk[b], 1);
      pg[off[b] + r] = (unsigned)sv[k] | ((unsigned)(dv[k] & 255) << 16);
    }
  }
}

// per-bucket exact node counts -> cnt (contiguous writes)
__global__ __launch_bounds__(256) void k_bcnt(const unsigned* __restrict__ pairs,
                                              const int* __restrict__ BB,
                                              int* __restrict__ cnt) {
  __shared__ int h[256];
  int k = blockIdx.x, g = blockIdx.y;
  h[threadIdx.x] = 0;
  __syncthreads();
  int lo = BB[g * (NBK + 1) + k], hi = BB[g * (NBK + 1) + k + 1];
  const unsigned* pg = pairs + (size_t)g * E;
  for (int i = lo + (int)threadIdx.x; i < hi; i += 256)
    atomicAdd(&h[(pg[i] >> 16) & 255], 1);
  __syncthreads();
  int n0 = k << 8;
  int nn = min(256, N - n0);
  if ((int)threadIdx.x < nn) cnt[g * N + n0 + threadIdx.x] = h[threadIdx.x];
}

// place srcs into col; scatter confined to the bucket's ~16KB col window
__global__ __launch_bounds__(256) void k_place(const unsigned* __restrict__ pairs,
                                               const int* __restrict__ BB,
                                               const int* __restrict__ rowptr,
                                               int* __restrict__ col) {
  __shared__ int rp[256];
  __shared__ int rk[256];
  int k = blockIdx.x, g = blockIdx.y;
  int n0 = k << 8;
  int nn = min(256, N - n0);
  if ((int)threadIdx.x < nn) rp[threadIdx.x] = rowptr[g * (N + 1) + n0 + threadIdx.x];
  rk[threadIdx.x] = 0;
  __syncthreads();
  int lo = BB[g * (NBK + 1) + k], hi = BB[g * (NBK + 1) + k + 1];
  const unsigned* pg = pairs + (size_t)g * E;
  int* cg = col + (size_t)g * E;
  for (int i = lo + (int)threadIdx.x; i < hi; i += 256) {
    unsigned p = pg[i];
    int dl = (p >> 16) & 255;
    int r = atomicAdd(&rk[dl], 1);
    cg[rp[dl] + r] = (int)(p & 0xffffu);
  }
}

// ---- 3-kernel exclusive scan of cnt -> rowptr (per graph) ----
__global__ void k_scan_partial(const int* __restrict__ cnt, int* __restrict__ part) {
  int g = blockIdx.y, b = blockIdx.x, tid = threadIdx.x;
  int base = b * 1024 + tid * 4;
  int s = 0;
#pragma unroll
  for (int k = 0; k < 4; ++k) {
    int i = base + k;
    if (i < N) s += cnt[g * N + i];
  }
  __shared__ int sm[256];
  sm[tid] = s;
  __syncthreads();
  for (int off = 128; off > 0; off >>= 1) {
    if (tid < off) sm[tid] += sm[tid + off];
    __syncthreads();
  }
  if (tid == 0) part[g * NB + b] = sm[0];
}

__global__ void k_scan_mid(int* __restrict__ part, int* __restrict__ rowptr) {
  int g = blockIdx.x;
  if (threadIdx.x != 0) return;
  int run = 0;
  for (int b = 0; b < NB; ++b) {
    int t = part[g * NB + b];
    part[g * NB + b] = run;
    run += t;
  }
  rowptr[g * (N + 1) + N] = run;  // == E
}

// final scan + fused dinv computation
__global__ void k_scan_final(const int* __restrict__ cnt, const int* __restrict__ part,
                             int* __restrict__ rowptr, float* __restrict__ dinv) {
  int g = blockIdx.y, b = blockIdx.x, tid = threadIdx.x;
  int base = b * 1024 + tid * 4;
  int c[4];
  int s = 0;
#pragma unroll
  for (int k = 0; k < 4; ++k) {
    int i = base + k;
    c[k] = (i < N) ? cnt[g * N + i] : 0;
    s += c[k];
  }
  __shared__ int sm[256];
  sm[tid] = s;
  __syncthreads();
  for (int off = 1; off < 256; off <<= 1) {
    int v = (tid >= off) ? sm[tid - off] : 0;
    __syncthreads();
    sm[tid] += v;
    __syncthreads();
  }
  int excl = sm[tid] - s + part[g * NB + b];
#pragma unroll
  for (int k = 0; k < 4; ++k) {
    int i = base + k;
    if (i < N) {
      rowptr[g * (N + 1) + i] = excl;
      dinv[g * N + i] = rsqrtf((float)(c[k] + 1));  // +1 self loop
    }
    excl += c[k];
  }
}

// ---------------- LDS-staged GEMM: columns across waves, lane = row ----------------
// Block = 256 threads = 4 waves, covers 64 rows. X tile staged ONCE in LDS
// (padded row stride K+1 -> (lane+k)%32 bank map, 2 lanes/bank = free).
// Wave w computes columns [w*F/4, (w+1)*F/4) for all 64 rows.
// c0 forced into an SGPR via readfirstlane so the W address chain is provably
// scalar -> batched s_load through the constant cache on the scalar pipe
// (R5 bug: threadIdx-derived c0 failed divergence analysis -> per-lane
// global_load_dword, VMEM-issue bound, 230 us).
template <int K, int F, bool PRESCALE, bool BIASELU, bool OUTH>
__global__ __launch_bounds__(256) void k_gemm_lds(const float* __restrict__ X,
                                                  const float* __restrict__ W,
                                                  const float* __restrict__ dinv,
                                                  const float* __restrict__ bias,
                                                  void* __restrict__ Hout) {
  constexpr int CH = F / 4;  // columns per wave (32 or 16)
  constexpr int PK = K + 1;  // padded LDS row stride
  __shared__ float xs[64 * PK];
  int g = blockIdx.y;
  int R0 = blockIdx.x * 64;
  // stage 64 rows (coalesced global read, conflict-free LDS write)
  for (int idx = threadIdx.x; idx < 64 * K; idx += 256) {
    int r = idx / K, k = idx - r * K;
    int row = R0 + r;
    xs[r * PK + k] = (row < N) ? X[((size_t)g * N + row) * K + k] : 0.f;
  }
  __syncthreads();
  int wv = threadIdx.x >> 6;
  int lane = threadIdx.x & 63;
  int c0 = __builtin_amdgcn_readfirstlane(wv * CH);  // SGPR column base
  const float* Wg = W + (size_t)g * K * F;
  const float* xrow = &xs[lane * PK];
  float acc[CH];
#pragma unroll
  for (int c = 0; c < CH; ++c) acc[c] = 0.f;
#pragma unroll 4
  for (int k = 0; k < K; ++k) {
    float xv = xrow[k];
#pragma unroll
    for (int c = 0; c < CH; ++c)
      acc[c] = fmaf(xv, Wg[(size_t)k * F + c0 + c], acc[c]);
  }
  int row = R0 + lane;
  if (row >= N) return;
  if constexpr (PRESCALE) {
    float sc = dinv[g * N + row];
#pragma unroll
    for (int c = 0; c < CH; ++c) acc[c] *= sc;
  }
  if constexpr (BIASELU) {
#pragma unroll
    for (int c = 0; c < CH; ++c) {
      float v = acc[c] + bias[g * F + c0 + c];
      acc[c] = v > 0.f ? v : expm1f(v);
    }
  }
  if constexpr (OUTH) {  // fp16 out (4x finer mantissa than bf16, same bytes)
    ushort* opb = (ushort*)Hout + ((size_t)g * N + row) * F + c0;
#pragma unroll
    for (int c4 = 0; c4 < CH; c4 += 4) {
      ushort4 o = {f2h(acc[c4]), f2h(acc[c4 + 1]), f2h(acc[c4 + 2]),
                   f2h(acc[c4 + 3])};
      *(ushort4*)(opb + c4) = o;
    }
  } else {
    float* op = (float*)Hout + ((size_t)g * N + row) * F + c0;
#pragma unroll
    for (int c4 = 0; c4 < CH; c4 += 4) {
      float4 o = {acc[c4], acc[c4 + 1], acc[c4 + 2], acc[c4 + 3]};
      *(float4*)(op + c4) = o;
    }
  }
}

// ---------------- aggregate-first (layer 1): Z = D^-1/2 (A+I) D^-1/2 X ----------------
// R10: one wave per dst node; d forced uniform -> col[j] addresses are
// wave-uniform from a const __restrict pointer -> scalar s_load through the
// constant cache (same mechanism as k_gemm_lds's W loads). No per-lane col
// load, NO ds_bpermute, no dinv gather (xh rows pre-scaled by dinv[s]).
// Per edge: 1 VMEM gather + cvt + add; SALU handles index/addr in parallel.
template <int F>
__global__ __launch_bounds__(256) void k_agg_in(const ushort* __restrict__ Xh,
                                                const int* __restrict__ rowptr,
                                                const int* __restrict__ col,
                                                const float* __restrict__ dinv,
                                                float* __restrict__ Z) {
  int g, chunk;
  xcd_map(blockIdx.x, g, chunk);
  int d = __builtin_amdgcn_readfirstlane(chunk * 4 + (threadIdx.x >> 6));
  int lane = threadIdx.x & 63;
  const ushort* hb = Xh + (size_t)g * N * F;
  const int* cl = col + (size_t)g * E;
  int rs = rowptr[g * (N + 1) + d];
  int re = rowptr[g * (N + 1) + d + 1];
  float acc = h2f(hb[(size_t)d * F + lane]);  // self loop (pre-scaled row)
  int j = rs;
  for (; j + 8 <= re; j += 8) {
    int s[8];
#pragma unroll
    for (int k = 0; k < 8; ++k) s[k] = cl[j + k];  // uniform -> s_load
    float v[8];
#pragma unroll
    for (int k = 0; k < 8; ++k) v[k] = h2f(hb[(size_t)s[k] * F + lane]);
#pragma unroll
    for (int k = 0; k < 8; ++k) acc += v[k];
  }
  for (; j < re; ++j) acc += h2f(hb[(size_t)cl[j] * F + lane]);
  Z[((size_t)g * N + d) * F + lane] = dinv[g * N + d] * acc;
}

// ---------------- aggregate-last (layer 2): out = ELU(dinv*(sum h2s) + b) ----------------
// h2s rows fp16, already pre-scaled by dinv[s] in the GEMM. Same scalar-index
// structure as k_agg_in.
template <int F>
__global__ __launch_bounds__(256) void k_agg_out(const ushort* __restrict__ Hsrc,
                                                 const int* __restrict__ rowptr,
                                                 const int* __restrict__ col,
                                                 const float* __restrict__ dinv,
                                                 const float* __restrict__ bias,
                                                 float* __restrict__ out) {
  int g, chunk;
  xcd_map(blockIdx.x, g, chunk);
  int d = __builtin_amdgcn_readfirstlane(chunk * 4 + (threadIdx.x >> 6));
  int lane = threadIdx.x & 63;
  const ushort* hb = Hsrc + (size_t)g * N * F;
  const int* cl = col + (size_t)g * E;
  int rs = rowptr[g * (N + 1) + d];
  int re = rowptr[g * (N + 1) + d + 1];
  float acc = h2f(hb[(size_t)d * F + lane]);  // self loop
  int j = rs;
  for (; j + 8 <= re; j += 8) {
    int s[8];
#pragma unroll
    for (int k = 0; k < 8; ++k) s[k] = cl[j + k];  // uniform -> s_load
    float v[8];
#pragma unroll
    for (int k = 0; k < 8; ++k) v[k] = h2f(hb[(size_t)s[k] * F + lane]);
#pragma unroll
    for (int k = 0; k < 8; ++k) acc += v[k];
  }
  for (; j < re; ++j) acc += h2f(hb[(size_t)cl[j] * F + lane]);
  float p = acc * dinv[g * N + d] + bias[g * F + lane];
  p = p > 0.f ? p : expm1f(p);
  out[((size_t)g * N + d) * F + lane] = p;
}

extern "C" void kernel_launch(void* const* d_in, const int* in_sizes, int n_in,
                              void* d_out, int out_size, void* d_ws, size_t ws_size,
                              hipStream_t stream) {
  const float* x = (const float*)d_in[0];
  const int* ei = (const int*)d_in[1];
  const float* W1 = (const float*)d_in[2];
  const float* b1 = (const float*)d_in[3];
  const float* W2 = (const float*)d_in[4];
  const float* b2 = (const float*)d_in[5];
  float* out = (float*)d_out;

  // Workspace carve-up (~169 MB; all radix/fp16 scratch aliased onto h1)
  char* p = (char*)d_ws;
  auto alloc = [&](size_t bytes) {
    char* r = p;
    p += (bytes + 255) & ~(size_t)255;
    return r;
  };
  int* cnt = (int*)alloc(sizeof(int) * G * N);
  int* rowptr = (int*)alloc(sizeof(int) * G * (N + 1));
  int* part = (int*)alloc(sizeof(int) * G * NB);
  float* dinv = (float*)alloc(sizeof(float) * G * N);
  int* col = (int*)alloc(sizeof(int) * (size_t)G * E);             // 12.8 MB
  float* z = (float*)alloc(sizeof(float) * (size_t)G * N * FIN);   // 51.2 MB
  float* h1 = (float*)alloc(sizeof(float) * (size_t)G * N * HID);  // 102.4 MB
  ushort* h2s = (ushort*)z;  // fp16, 25.6 MB; reuses z (dead after gemm1)
  // Radix + fp16-x scratch aliased into h1 (all dead before gemm1 writes h1):
  unsigned* pairs = (unsigned*)h1;                         // 12.8 MB
  int* PH = (int*)((char*)h1 + ((size_t)13 << 20));        // G*NBK*PB*4 = 200KB
  int* POFF = (int*)((char*)h1 + ((size_t)14 << 20));      // 200KB
  int* BB = (int*)((char*)h1 + ((size_t)15 << 20));        // G*(NBK+1)*4 = 3.2KB
  ushort* xh = (ushort*)((char*)h1 + ((size_t)32 << 20));  // fp16 x, 25.6 MB

  // 1. CSR build via two-pass radix partition (line-contiguous writes only)
  k_phist<<<dim3(PB, G), 256, 0, stream>>>(ei, PH);
  k_pscan<<<G, 256, 0, stream>>>(PH, POFF, BB);
  k_part<<<dim3(PB, G), 256, 0, stream>>>(ei, POFF, pairs);
  k_bcnt<<<dim3(NBK, G), 256, 0, stream>>>(pairs, BB, cnt);
  dim3 sg(NB, G);
  k_scan_partial<<<sg, 256, 0, stream>>>(cnt, part);
  k_scan_mid<<<G, 64, 0, stream>>>(part, rowptr);
  k_scan_final<<<sg, 256, 0, stream>>>(cnt, part, rowptr, dinv);
  k_place<<<dim3(NBK, G), 256, 0, stream>>>(pairs, BB, rowptr, col);

  // 2. x -> fp16 pre-scaled by dinv (after scans; removes per-edge dinv work)
  k_x2h<<<(G * N * FIN / 4 + 255) / 256, 256, 0, stream>>>(
      (const float4*)x, dinv, (ushort4*)xh, G * N * FIN / 4);

  // 3. layer 1: aggregate-first (scalar-index fp16 gathers), then LDS-GEMM+bias+ELU
  k_agg_in<FIN><<<(G * N) / 4, 256, 0, stream>>>(xh, rowptr, col, dinv, z);
  dim3 gg((N + 63) / 64, G);
  k_gemm_lds<FIN, HID, false, true, false>
      <<<gg, 256, 0, stream>>>(z, W1, nullptr, b1, h1);

  // 4. layer 2: transform-first 128->64 (pre-scaled, fp16 out), then aggregate
  k_gemm_lds<HID, FOUT, true, false, true>
      <<<gg, 256, 0, stream>>>(h1, W2, dinv, nullptr, h2s);
  k_agg_out<FOUT><<<(G * N) / 4, 256, 0, stream>>>(h2s, rowptr, col, dinv, b2, out);
}